// Round 7
// baseline (551.269 us; speedup 1.0000x reference)
//
#include <hip/hip_runtime.h>
#include <cstddef>

#define NS 64000
#define GROUP 8000
#define TM 64

typedef __bf16 bf16x8 __attribute__((ext_vector_type(8)));
typedef float floatx4 __attribute__((ext_vector_type(4)));
typedef unsigned short ushort_t;

// ---------------- ws layout (bytes): only mixed weights now ----------------
static const size_t BY_W0 = 0;                      // 8*192*192*2 = 589824
static const size_t BY_W1 = BY_W0 + 589824;         // 8*256*256*2 = 1048576
static const size_t BY_W2 = BY_W1 + 1048576;        // 8*128*128*2 = 262144
static const size_t BY_B0 = BY_W2 + 262144;         // 8*192*4     = 6144

__device__ __forceinline__ unsigned short f2bf(float f) {
    unsigned u = __float_as_uint(f);
    u += 0x7fff + ((u >> 16) & 1);   // RNE
    return (unsigned short)(u >> 16);
}

// ---------------- expert-mix kernel (bf16 weights out) ----------------
__global__ __launch_bounds__(256) void mix_kernel(
    const float* __restrict__ coef,
    const float* __restrict__ w_m0, const float* __restrict__ b_m0,
    const float* __restrict__ ws_m0, const float* __restrict__ bs_m0,
    const float* __restrict__ w_m1, const float* __restrict__ ws_m1,
    const float* __restrict__ w_m2, const float* __restrict__ ws_m2,
    ushort_t* __restrict__ W0, float* __restrict__ B0,
    ushort_t* __restrict__ W1, ushort_t* __restrict__ W2)
{
    int tid = blockIdx.x * 256 + threadIdx.x;
    if (tid < 294912) {
        int b = tid / 36864, rem = tid % 36864;
        float s = ws_m0[rem];
        #pragma unroll
        for (int e = 0; e < 8; e++) s += coef[b * 8 + e] * w_m0[e * 36864 + rem];
        W0[tid] = f2bf(s);
    } else if (tid < 296448) {
        int i2 = tid - 294912;
        int b = i2 / 192, o = i2 % 192;
        float s = bs_m0[o];
        #pragma unroll
        for (int e = 0; e < 8; e++) s += coef[b * 8 + e] * b_m0[e * 192 + o];
        B0[i2] = s;
    } else if (tid < 820736) {
        // W1big[b,o,i] (256x256): [[Wr,-Wi],[Wi,Wr]] fold of mixed 256x128 w_m1
        int i3 = tid - 296448;
        int b = i3 >> 16, rem = i3 & 65535;
        int o = rem >> 8, i = rem & 255;
        int r, cc; float sign = 1.0f;
        if (o < 128) { if (i < 128) { r = o;       cc = i; } else { r = 128 + o;      cc = i - 128; sign = -1.0f; } }
        else { int o2 = o - 128; if (i < 128) { r = 128 + o2; cc = i; } else { r = o2; cc = i - 128; } }
        int idx = r * 128 + cc;
        float s = ws_m1[idx];
        #pragma unroll
        for (int e = 0; e < 8; e++) s += coef[b * 8 + e] * w_m1[e * 32768 + idx];
        W1[i3] = f2bf(sign * s);
    } else if (tid < 951808) {
        int i4 = tid - 820736;
        int b = i4 >> 14, rem = i4 & 16383;
        int o = rem >> 7, i = rem & 127;
        int r, cc; float sign = 1.0f;
        if (o < 64) { if (i < 64) { r = o;      cc = i; } else { r = 64 + o;      cc = i - 64; sign = -1.0f; } }
        else { int o2 = o - 64; if (i < 64) { r = 64 + o2; cc = i; } else { r = o2; cc = i - 64; } }
        int idx = r * 64 + cc;
        float s = ws_m2[idx];
        #pragma unroll
        for (int e = 0; e < 8; e++) s += coef[b * 8 + e] * w_m2[e * 8192 + idx];
        W2[i4] = f2bf(sign * s);
    }
}

// ---------------- rotation helpers ----------------
__device__ __forceinline__ void zrot1(float& v0, float& v2, float c, float s) {
    float t0 = c * v0 + s * v2;
    v2 = -s * v0 + c * v2;
    v0 = t0;
}
__device__ __forceinline__ void j1mul(const float* J, float& v0, float& v1, float& v2) {
    float w0 = J[0] * v0 + J[1] * v1 + J[2] * v2;
    float w1 = J[3] * v0 + J[4] * v1 + J[5] * v2;
    float w2 = J[6] * v0 + J[7] * v1 + J[8] * v2;
    v0 = w0; v1 = w1; v2 = w2;
}
__device__ __forceinline__ void zrot2(float& u0, float& u1, float& u3, float& u4,
                                      float c1, float s1, float c2, float s2) {
    float t0 = c2 * u0 + s2 * u4;
    u4 = -s2 * u0 + c2 * u4;
    u0 = t0;
    float t1 = c1 * u1 + s1 * u3;
    u3 = -s1 * u1 + c1 * u3;
    u1 = t1;
}
__device__ __forceinline__ void j2mul(const float* J, float& u0, float& u1, float& u2, float& u3, float& u4) {
    float w0 = J[0]  * u0 + J[1]  * u1 + J[2]  * u2 + J[3]  * u3 + J[4]  * u4;
    float w1 = J[5]  * u0 + J[6]  * u1 + J[7]  * u2 + J[8]  * u3 + J[9]  * u4;
    float w2 = J[10] * u0 + J[11] * u1 + J[12] * u2 + J[13] * u3 + J[14] * u4;
    float w3 = J[15] * u0 + J[16] * u1 + J[17] * u2 + J[18] * u3 + J[19] * u4;
    float w4 = J[20] * u0 + J[21] * u1 + J[22] * u2 + J[23] * u3 + J[24] * u4;
    u0 = w0; u1 = w1; u2 = w2; u3 = w3; u4 = w4;
}

// swizzled LDS element index: row-major [row][K], 16B granules XOR'd by row&7.
// valid since K/8 is a multiple of 8 for K in {128,192,256}.
__device__ __forceinline__ int sidx(int row, int k, int K) {
    int gr = (k >> 3) ^ (row & 7);
    return row * K + gr * 8 + (k & 7);
}
__device__ __forceinline__ float yread(const ushort_t* L, int row, int k, int K) {
    unsigned u = L[sidx(row, k, K)];
    return __uint_as_float(u << 16);
}

// ---------------- per-wave GEMM segment: acc[t][ms] += X(LDS) * Wseg(rows t*16+mi) ----------------
template<int K, int NT>
__device__ __forceinline__ void gemm_seg(
    floatx4 (*acc)[4],
    const ushort_t* __restrict__ Wseg,   // global (L2-resident), row-major, length-K rows
    const ushort_t* XL_,                 // LDS region, swizzled
    int mi, int quad)
{
    #pragma unroll
    for (int k0 = 0; k0 < K; k0 += 32) {
        bf16x8 af[4];
        #pragma unroll
        for (int ms = 0; ms < 4; ms++) {
            int row = ms * 16 + mi;
            int gr = ((k0 >> 3) + quad) ^ (row & 7);
            af[ms] = *(const bf16x8*)&XL_[row * K + gr * 8];
        }
        bf16x8 bfr[NT];
        #pragma unroll
        for (int t = 0; t < NT; t++)
            bfr[t] = *(const bf16x8*)&Wseg[(size_t)(t * 16 + mi) * K + k0 + quad * 8];
        #pragma unroll
        for (int t = 0; t < NT; t++)
            #pragma unroll
            for (int ms = 0; ms < 4; ms++)
                acc[t][ms] = __builtin_amdgcn_mfma_f32_16x16x32_bf16(af[ms], bfr[t], acc[t][ms], 0, 0, 0);
    }
}

// write acc tiles into LDS Y (bf16, same swizzled layout), optional bias add
template<int K, int NT, bool BIAS>
__device__ __forceinline__ void ywrite(
    floatx4 (*acc)[4], ushort_t* L, int n0, const float* __restrict__ bias,
    int mi, int quad)
{
    #pragma unroll
    for (int t = 0; t < NT; t++) {
        int col = n0 + t * 16 + mi;
        float bv = BIAS ? bias[col] : 0.f;
        int gc = col >> 3, kw = col & 7;
        #pragma unroll
        for (int ms = 0; ms < 4; ms++) {
            #pragma unroll
            for (int r = 0; r < 4; r++) {
                int m = ms * 16 + quad * 4 + r;
                L[m * K + ((gc ^ (m & 7)) * 8) + kw] = f2bf(acc[t][ms][r] + bv);
            }
        }
    }
}

// ---------------- fused: rotate -> 3 GEMMs -> inverse rotate ----------------
// R0 structure (best measured: 138 us). MARGINAL-COST PROBE: phase B runs
// REPB times. acc is re-initialized each rep from an OPAQUE zero (asm-laundered)
// so the loop-invariant GEMM cannot be LICM-hoisted and non-final reps cannot
// be DCE'd (rule #17). Output is bit-identical to R0.
#define REPB 3
__global__ __launch_bounds__(256, 2) void fused_kernel(
    const float* __restrict__ x,
    const float* __restrict__ alpha, const float* __restrict__ beta, const float* __restrict__ gamma_,
    const float* __restrict__ Jd1, const float* __restrict__ Jd2,
    const ushort_t* __restrict__ W0, const ushort_t* __restrict__ W1, const ushort_t* __restrict__ W2,
    const float* __restrict__ B0,
    float* __restrict__ out)
{
    __shared__ ushort_t XL[36864];   // X then Y: X0(64x192) | X1(64x256) | X2(64x128)
    __shared__ float TR[64 * 6];
    __shared__ float JL[34];

    ushort_t* X0L = XL;
    ushort_t* X1L = XL + 12288;
    ushort_t* X2L = XL + 28672;

    int t = threadIdx.x;
    int w = t >> 6, lane = t & 63;
    int g = blockIdx.x / 125;
    int base = g * GROUP + (blockIdx.x % 125) * TM;

    if (t < 64) {
        int n = base + t;
        float sa, ca, sb, cb, sg, cg;
        __sincosf(alpha[n],  &sa, &ca);
        __sincosf(beta[n],   &sb, &cb);
        __sincosf(gamma_[n], &sg, &cg);
        TR[t * 6 + 0] = sa; TR[t * 6 + 1] = ca;
        TR[t * 6 + 2] = sb; TR[t * 6 + 3] = cb;
        TR[t * 6 + 4] = sg; TR[t * 6 + 5] = cg;
    } else if (t < 98) {
        int j = t - 64;
        JL[j] = (j < 9) ? Jd1[j] : Jd2[j - 9];
    }
    __syncthreads();

    const float* J1 = JL;
    const float* J2 = JL + 9;
    int c = lane;

    // ---- phase A: forward rotate x -> LDS bf16 ----
    for (int i = 0; i < 16; i++) {
        int nl = w * 16 + i;
        const float* xr = x + (size_t)(base + nl) * 576;
        float sa = TR[nl * 6 + 0], ca = TR[nl * 6 + 1];
        float sb = TR[nl * 6 + 2], cb = TR[nl * 6 + 3];
        float sg = TR[nl * 6 + 4], cg = TR[nl * 6 + 5];
        float s2a = 2.f * sa * ca, c2a = ca * ca - sa * sa;
        float s2b = 2.f * sb * cb, c2b = cb * cb - sb * sb;
        float s2g = 2.f * sg * cg, c2g = cg * cg - sg * sg;

        float v0 = xr[64 + 3 * c], v1 = xr[64 + 3 * c + 1], v2 = xr[64 + 3 * c + 2];
        zrot1(v0, v2, cg, sg);
        j1mul(J1, v0, v1, v2);
        zrot1(v0, v2, cb, sb);
        j1mul(J1, v0, v1, v2);
        zrot1(v0, v2, ca, sa);

        float u0 = xr[256 + 5 * c], u1 = xr[256 + 5 * c + 1], u2 = xr[256 + 5 * c + 2],
              u3 = xr[256 + 5 * c + 3], u4 = xr[256 + 5 * c + 4];
        zrot2(u0, u1, u3, u4, cg, sg, c2g, s2g);
        j2mul(J2, u0, u1, u2, u3, u4);
        zrot2(u0, u1, u3, u4, cb, sb, c2b, s2b);
        j2mul(J2, u0, u1, u2, u3, u4);
        zrot2(u0, u1, u3, u4, ca, sa, c2a, s2a);

        X0L[sidx(nl, c, 192)]       = f2bf(xr[c]);
        X0L[sidx(nl, 64 + c, 192)]  = f2bf(v1);
        X0L[sidx(nl, 128 + c, 192)] = f2bf(u2);
        X1L[sidx(nl, c, 256)]       = f2bf(v0);
        X1L[sidx(nl, 64 + c, 256)]  = f2bf(u1);
        X1L[sidx(nl, 128 + c, 256)] = f2bf(v2);
        X1L[sidx(nl, 192 + c, 256)] = f2bf(u3);
        X2L[sidx(nl, c, 128)]       = f2bf(u0);
        X2L[sidx(nl, 64 + c, 128)]  = f2bf(u4);
    }
    __syncthreads();

    // ---- phase B: MFMA GEMMs, B-fragments streamed from L2 ----
    int mi = lane & 15, quad = lane >> 4;
    floatx4 acc[10][4];

    const ushort_t* W0g = W0 + (size_t)g * 192 * 192;
    const ushort_t* W1g = W1 + (size_t)g * 256 * 256;
    const ushort_t* W2g = W2 + (size_t)g * 128 * 128;

    #pragma unroll 1
    for (int rep = 0; rep < REPB; ++rep) {
        // opaque zero: per-iteration asm output, so the GEMM below is not
        // loop-invariant (no LICM) and every rep's chain is live (no DCE).
        floatx4 z = (floatx4)0.f;
        asm volatile("" : "+v"(z));
        #pragma unroll
        for (int a = 0; a < 10; a++)
            #pragma unroll
            for (int b2 = 0; b2 < 4; b2++) acc[a][b2] = z;

        if (w == 0) {
            gemm_seg<192, 10>(acc, W0g, X0L, mi, quad);                       // Y0 cols 0..159
        } else if (w == 1) {
            gemm_seg<256, 8>(acc, W1g, X1L, mi, quad);                        // Y1 cols 0..127
        } else if (w == 2) {
            gemm_seg<256, 8>(acc, W1g + (size_t)128 * 256, X1L, mi, quad);    // Y1 cols 128..255
        } else {
            gemm_seg<192, 2>(acc, W0g + (size_t)160 * 192, X0L, mi, quad);    // Y0 cols 160..191
            gemm_seg<128, 8>(acc + 2, W2g, X2L, mi, quad);                    // Y2 cols 0..127
        }

        // consume every rep's results (second line of defense vs DCE)
        #pragma unroll
        for (int a = 0; a < 10; a++)
            #pragma unroll
            for (int b2 = 0; b2 < 4; b2++)
                asm volatile("" :: "v"(acc[a][b2]));
    }

    __syncthreads();   // everyone done reading X from LDS

    const float* B0g = B0 + g * 192;
    if (w == 0) {
        ywrite<192, 10, true>(acc, X0L, 0, B0g, mi, quad);
    } else if (w == 1) {
        ywrite<256, 8, false>(acc, X1L, 0, nullptr, mi, quad);
    } else if (w == 2) {
        ywrite<256, 8, false>(acc, X1L, 128, nullptr, mi, quad);
    } else {
        ywrite<192, 2, true>(acc, X0L, 160, B0g, mi, quad);
        ywrite<128, 8, false>(acc + 2, X2L, 0, nullptr, mi, quad);
    }
    __syncthreads();

    // ---- phase C: inverse rotate Y(LDS) -> out ----
    for (int i = 0; i < 16; i++) {
        int nl = w * 16 + i;
        float sa = -TR[nl * 6 + 0], ca = TR[nl * 6 + 1];
        float sb = -TR[nl * 6 + 2], cb = TR[nl * 6 + 3];
        float sg = -TR[nl * 6 + 4], cg = TR[nl * 6 + 5];
        float s2a = 2.f * sa * ca, c2a = ca * ca - sa * sa;
        float s2b = 2.f * sb * cb, c2b = cb * cb - sb * sb;
        float s2g = 2.f * sg * cg, c2g = cg * cg - sg * sg;

        float* orow = out + (size_t)(base + nl) * 576;

        orow[c] = yread(X0L, nl, c, 192);

        float v0 = yread(X1L, nl, c, 256);
        float v1 = yread(X0L, nl, 64 + c, 192);
        float v2 = yread(X1L, nl, 128 + c, 256);
        zrot1(v0, v2, ca, sa);
        j1mul(J1, v0, v1, v2);
        zrot1(v0, v2, cb, sb);
        j1mul(J1, v0, v1, v2);
        zrot1(v0, v2, cg, sg);
        orow[64 + 3 * c]     = v0;
        orow[64 + 3 * c + 1] = v1;
        orow[64 + 3 * c + 2] = v2;

        float u0 = yread(X2L, nl, c, 128);
        float u1 = yread(X1L, nl, 64 + c, 256);
        float u2 = yread(X0L, nl, 128 + c, 192);
        float u3 = yread(X1L, nl, 192 + c, 256);
        float u4 = yread(X2L, nl, 64 + c, 128);
        zrot2(u0, u1, u3, u4, ca, sa, c2a, s2a);
        j2mul(J2, u0, u1, u2, u3, u4);
        zrot2(u0, u1, u3, u4, cb, sb, c2b, s2b);
        j2mul(J2, u0, u1, u2, u3, u4);
        zrot2(u0, u1, u3, u4, cg, sg, c2g, s2g);
        orow[256 + 5 * c]     = u0;
        orow[256 + 5 * c + 1] = u1;
        orow[256 + 5 * c + 2] = u2;
        orow[256 + 5 * c + 3] = u3;
        orow[256 + 5 * c + 4] = u4;
    }
}

extern "C" void kernel_launch(void* const* d_in, const int* in_sizes, int n_in,
                              void* d_out, int out_size, void* d_ws, size_t ws_size,
                              hipStream_t stream)
{
    const float* x      = (const float*)d_in[0];
    const float* alpha  = (const float*)d_in[1];
    const float* beta   = (const float*)d_in[2];
    const float* gamma_ = (const float*)d_in[3];
    const float* coef   = (const float*)d_in[4];
    const float* Jd1    = (const float*)d_in[5];
    const float* Jd2    = (const float*)d_in[6];
    const float* w_m0   = (const float*)d_in[7];
    const float* b_m0   = (const float*)d_in[8];
    const float* ws_m0  = (const float*)d_in[9];
    const float* bs_m0  = (const float*)d_in[10];
    const float* w_m1   = (const float*)d_in[11];
    const float* ws_m1  = (const float*)d_in[12];
    const float* w_m2   = (const float*)d_in[13];
    const float* ws_m2  = (const float*)d_in[14];

    char* wsb = (char*)d_ws;
    ushort_t* W0 = (ushort_t*)(wsb + BY_W0);
    ushort_t* W1 = (ushort_t*)(wsb + BY_W1);
    ushort_t* W2 = (ushort_t*)(wsb + BY_W2);
    float*    B0 = (float*)(wsb + BY_B0);
    float*    out = (float*)d_out;

    hipLaunchKernelGGL(mix_kernel, dim3(3718), dim3(256), 0, stream,
                       coef, w_m0, b_m0, ws_m0, bs_m0, w_m1, ws_m1, w_m2, ws_m2,
                       W0, B0, W1, W2);
    hipLaunchKernelGGL(fused_kernel, dim3(1000), dim3(256), 0, stream,
                       x, alpha, beta, gamma_, Jd1, Jd2, W0, W1, W2, B0, out);
}

// Round 8
// 330.792 us; speedup vs baseline: 1.6665x; 1.6665x over previous
//
#include <hip/hip_runtime.h>
#include <cstddef>

#define NS 64000
#define GROUP 8000
#define TM 64

typedef __bf16 bf16x8 __attribute__((ext_vector_type(8)));
typedef float floatx4 __attribute__((ext_vector_type(4)));
typedef unsigned short ushort_t;

// ---------------- ws layout (bytes): only mixed weights now ----------------
static const size_t BY_W0 = 0;                      // 8*192*192*2 = 589824
static const size_t BY_W1 = BY_W0 + 589824;         // 8*256*256*2 = 1048576
static const size_t BY_W2 = BY_W1 + 1048576;        // 8*128*128*2 = 262144
static const size_t BY_B0 = BY_W2 + 262144;         // 8*192*4     = 6144

__device__ __forceinline__ unsigned short f2bf(float f) {
    unsigned u = __float_as_uint(f);
    u += 0x7fff + ((u >> 16) & 1);   // RNE
    return (unsigned short)(u >> 16);
}

// ---------------- expert-mix kernel (bf16 weights out) ----------------
__global__ __launch_bounds__(256) void mix_kernel(
    const float* __restrict__ coef,
    const float* __restrict__ w_m0, const float* __restrict__ b_m0,
    const float* __restrict__ ws_m0, const float* __restrict__ bs_m0,
    const float* __restrict__ w_m1, const float* __restrict__ ws_m1,
    const float* __restrict__ w_m2, const float* __restrict__ ws_m2,
    ushort_t* __restrict__ W0, float* __restrict__ B0,
    ushort_t* __restrict__ W1, ushort_t* __restrict__ W2)
{
    int tid = blockIdx.x * 256 + threadIdx.x;
    if (tid < 294912) {
        int b = tid / 36864, rem = tid % 36864;
        float s = ws_m0[rem];
        #pragma unroll
        for (int e = 0; e < 8; e++) s += coef[b * 8 + e] * w_m0[e * 36864 + rem];
        W0[tid] = f2bf(s);
    } else if (tid < 296448) {
        int i2 = tid - 294912;
        int b = i2 / 192, o = i2 % 192;
        float s = bs_m0[o];
        #pragma unroll
        for (int e = 0; e < 8; e++) s += coef[b * 8 + e] * b_m0[e * 192 + o];
        B0[i2] = s;
    } else if (tid < 820736) {
        // W1big[b,o,i] (256x256): [[Wr,-Wi],[Wi,Wr]] fold of mixed 256x128 w_m1
        int i3 = tid - 296448;
        int b = i3 >> 16, rem = i3 & 65535;
        int o = rem >> 8, i = rem & 255;
        int r, cc; float sign = 1.0f;
        if (o < 128) { if (i < 128) { r = o;       cc = i; } else { r = 128 + o;      cc = i - 128; sign = -1.0f; } }
        else { int o2 = o - 128; if (i < 128) { r = 128 + o2; cc = i; } else { r = o2; cc = i - 128; } }
        int idx = r * 128 + cc;
        float s = ws_m1[idx];
        #pragma unroll
        for (int e = 0; e < 8; e++) s += coef[b * 8 + e] * w_m1[e * 32768 + idx];
        W1[i3] = f2bf(sign * s);
    } else if (tid < 951808) {
        int i4 = tid - 820736;
        int b = i4 >> 14, rem = i4 & 16383;
        int o = rem >> 7, i = rem & 127;
        int r, cc; float sign = 1.0f;
        if (o < 64) { if (i < 64) { r = o;      cc = i; } else { r = 64 + o;      cc = i - 64; sign = -1.0f; } }
        else { int o2 = o - 64; if (i < 64) { r = 64 + o2; cc = i; } else { r = o2; cc = i - 64; } }
        int idx = r * 64 + cc;
        float s = ws_m2[idx];
        #pragma unroll
        for (int e = 0; e < 8; e++) s += coef[b * 8 + e] * w_m2[e * 8192 + idx];
        W2[i4] = f2bf(sign * s);
    }
}

// ---------------- rotation helpers ----------------
__device__ __forceinline__ void zrot1(float& v0, float& v2, float c, float s) {
    float t0 = c * v0 + s * v2;
    v2 = -s * v0 + c * v2;
    v0 = t0;
}
__device__ __forceinline__ void j1mul(const float* J, float& v0, float& v1, float& v2) {
    float w0 = J[0] * v0 + J[1] * v1 + J[2] * v2;
    float w1 = J[3] * v0 + J[4] * v1 + J[5] * v2;
    float w2 = J[6] * v0 + J[7] * v1 + J[8] * v2;
    v0 = w0; v1 = w1; v2 = w2;
}
__device__ __forceinline__ void zrot2(float& u0, float& u1, float& u3, float& u4,
                                      float c1, float s1, float c2, float s2) {
    float t0 = c2 * u0 + s2 * u4;
    u4 = -s2 * u0 + c2 * u4;
    u0 = t0;
    float t1 = c1 * u1 + s1 * u3;
    u3 = -s1 * u1 + c1 * u3;
    u1 = t1;
}
__device__ __forceinline__ void j2mul(const float* J, float& u0, float& u1, float& u2, float& u3, float& u4) {
    float w0 = J[0]  * u0 + J[1]  * u1 + J[2]  * u2 + J[3]  * u3 + J[4]  * u4;
    float w1 = J[5]  * u0 + J[6]  * u1 + J[7]  * u2 + J[8]  * u3 + J[9]  * u4;
    float w2 = J[10] * u0 + J[11] * u1 + J[12] * u2 + J[13] * u3 + J[14] * u4;
    float w3 = J[15] * u0 + J[16] * u1 + J[17] * u2 + J[18] * u3 + J[19] * u4;
    float w4 = J[20] * u0 + J[21] * u1 + J[22] * u2 + J[23] * u3 + J[24] * u4;
    u0 = w0; u1 = w1; u2 = w2; u3 = w3; u4 = w4;
}

// swizzled LDS element index: row-major [row][K], 16B granules XOR'd by row&7.
// valid since K/8 is a multiple of 8 for K in {128,192,256}.
__device__ __forceinline__ int sidx(int row, int k, int K) {
    int gr = (k >> 3) ^ (row & 7);
    return row * K + gr * 8 + (k & 7);
}
__device__ __forceinline__ float yread(const ushort_t* L, int row, int k, int K) {
    unsigned u = L[sidx(row, k, K)];
    return __uint_as_float(u << 16);
}

// load one row's 9 channel values for lane channel c (compiler merges adjacents)
__device__ __forceinline__ void load_row(const float* __restrict__ x, int n, int c, float* v) {
    const float* xr = x + (size_t)n * 576;
    v[0] = xr[c];
    v[1] = xr[64 + 3 * c];  v[2] = xr[64 + 3 * c + 1];  v[3] = xr[64 + 3 * c + 2];
    v[4] = xr[256 + 5 * c]; v[5] = xr[256 + 5 * c + 1]; v[6] = xr[256 + 5 * c + 2];
    v[7] = xr[256 + 5 * c + 3]; v[8] = xr[256 + 5 * c + 4];
}

// ---------------- per-wave GEMM segment: acc[t][ms] += X(LDS) * Wseg(rows t*16+mi) ----------------
template<int K, int NT>
__device__ __forceinline__ void gemm_seg(
    floatx4 (*acc)[4],
    const ushort_t* __restrict__ Wseg,   // global (L2-resident), row-major, length-K rows
    const ushort_t* XL_,                 // LDS region, swizzled
    int mi, int quad)
{
    #pragma unroll
    for (int k0 = 0; k0 < K; k0 += 32) {
        bf16x8 af[4];
        #pragma unroll
        for (int ms = 0; ms < 4; ms++) {
            int row = ms * 16 + mi;
            int gr = ((k0 >> 3) + quad) ^ (row & 7);
            af[ms] = *(const bf16x8*)&XL_[row * K + gr * 8];
        }
        bf16x8 bfr[NT];
        #pragma unroll
        for (int t = 0; t < NT; t++)
            bfr[t] = *(const bf16x8*)&Wseg[(size_t)(t * 16 + mi) * K + k0 + quad * 8];
        #pragma unroll
        for (int t = 0; t < NT; t++)
            #pragma unroll
            for (int ms = 0; ms < 4; ms++)
                acc[t][ms] = __builtin_amdgcn_mfma_f32_16x16x32_bf16(af[ms], bfr[t], acc[t][ms], 0, 0, 0);
    }
}

// write acc tiles into LDS Y (bf16, same swizzled layout), optional bias add
template<int K, int NT, bool BIAS>
__device__ __forceinline__ void ywrite(
    floatx4 (*acc)[4], ushort_t* L, int n0, const float* __restrict__ bias,
    int mi, int quad)
{
    #pragma unroll
    for (int t = 0; t < NT; t++) {
        int col = n0 + t * 16 + mi;
        float bv = BIAS ? bias[col] : 0.f;
        int gc = col >> 3, kw = col & 7;
        #pragma unroll
        for (int ms = 0; ms < 4; ms++) {
            #pragma unroll
            for (int r = 0; r < 4; r++) {
                int m = ms * 16 + quad * 4 + r;
                L[m * K + ((gc ^ (m & 7)) * 8) + kw] = f2bf(acc[t][ms][r] + bv);
            }
        }
    }
}

// ---------------- fused: rotate -> 3 GEMMs -> inverse rotate ----------------
// Exact R0 structure (best measured: 138 us) with ONE change: phase A is
// pair-pipelined with a 2-row-ahead register prefetch, breaking the serial
// per-row load->rotate latency chain (loads for pair k+1 in flight while
// pair k rotates). Fully unrolled so all buffer indices are static (rule #20).
__global__ __launch_bounds__(256, 2) void fused_kernel(
    const float* __restrict__ x,
    const float* __restrict__ alpha, const float* __restrict__ beta, const float* __restrict__ gamma_,
    const float* __restrict__ Jd1, const float* __restrict__ Jd2,
    const ushort_t* __restrict__ W0, const ushort_t* __restrict__ W1, const ushort_t* __restrict__ W2,
    const float* __restrict__ B0,
    float* __restrict__ out)
{
    __shared__ ushort_t XL[36864];   // X then Y: X0(64x192) | X1(64x256) | X2(64x128)
    __shared__ float TR[64 * 6];
    __shared__ float JL[34];

    ushort_t* X0L = XL;
    ushort_t* X1L = XL + 12288;
    ushort_t* X2L = XL + 28672;

    int t = threadIdx.x;
    int w = t >> 6, lane = t & 63;
    int g = blockIdx.x / 125;
    int base = g * GROUP + (blockIdx.x % 125) * TM;

    if (t < 64) {
        int n = base + t;
        float sa, ca, sb, cb, sg, cg;
        __sincosf(alpha[n],  &sa, &ca);
        __sincosf(beta[n],   &sb, &cb);
        __sincosf(gamma_[n], &sg, &cg);
        TR[t * 6 + 0] = sa; TR[t * 6 + 1] = ca;
        TR[t * 6 + 2] = sb; TR[t * 6 + 3] = cb;
        TR[t * 6 + 4] = sg; TR[t * 6 + 5] = cg;
    } else if (t < 98) {
        int j = t - 64;
        JL[j] = (j < 9) ? Jd1[j] : Jd2[j - 9];
    }
    __syncthreads();

    const float* J1 = JL;
    const float* J2 = JL + 9;
    int c = lane;

    // ---- phase A: forward rotate x -> LDS bf16 (pair-pipelined, 2-row prefetch) ----
    {
        float pa[18], pb[18];
        int r0 = w * 16;
        load_row(x, base + r0 + 0, c, pa);
        load_row(x, base + r0 + 1, c, pa + 9);
        #pragma unroll
        for (int ii = 0; ii < 8; ii++) {
            float* cu = (ii & 1) ? pb : pa;
            float* nx = (ii & 1) ? pa : pb;
            if (ii < 7) {
                load_row(x, base + r0 + 2 * ii + 2, c, nx);
                load_row(x, base + r0 + 2 * ii + 3, c, nx + 9);
            }
            #pragma unroll
            for (int h = 0; h < 2; h++) {
                int nl = r0 + 2 * ii + h;
                const float* cv = cu + 9 * h;
                float sa = TR[nl * 6 + 0], ca = TR[nl * 6 + 1];
                float sb = TR[nl * 6 + 2], cb = TR[nl * 6 + 3];
                float sg = TR[nl * 6 + 4], cg = TR[nl * 6 + 5];
                float s2a = 2.f * sa * ca, c2a = ca * ca - sa * sa;
                float s2b = 2.f * sb * cb, c2b = cb * cb - sb * sb;
                float s2g = 2.f * sg * cg, c2g = cg * cg - sg * sg;

                float v0 = cv[1], v1 = cv[2], v2 = cv[3];
                zrot1(v0, v2, cg, sg);
                j1mul(J1, v0, v1, v2);
                zrot1(v0, v2, cb, sb);
                j1mul(J1, v0, v1, v2);
                zrot1(v0, v2, ca, sa);

                float u0 = cv[4], u1 = cv[5], u2 = cv[6], u3 = cv[7], u4 = cv[8];
                zrot2(u0, u1, u3, u4, cg, sg, c2g, s2g);
                j2mul(J2, u0, u1, u2, u3, u4);
                zrot2(u0, u1, u3, u4, cb, sb, c2b, s2b);
                j2mul(J2, u0, u1, u2, u3, u4);
                zrot2(u0, u1, u3, u4, ca, sa, c2a, s2a);

                X0L[sidx(nl, c, 192)]       = f2bf(cv[0]);
                X0L[sidx(nl, 64 + c, 192)]  = f2bf(v1);
                X0L[sidx(nl, 128 + c, 192)] = f2bf(u2);
                X1L[sidx(nl, c, 256)]       = f2bf(v0);
                X1L[sidx(nl, 64 + c, 256)]  = f2bf(u1);
                X1L[sidx(nl, 128 + c, 256)] = f2bf(v2);
                X1L[sidx(nl, 192 + c, 256)] = f2bf(u3);
                X2L[sidx(nl, c, 128)]       = f2bf(u0);
                X2L[sidx(nl, 64 + c, 128)]  = f2bf(u4);
            }
        }
    }
    __syncthreads();

    // ---- phase B: MFMA GEMMs, B-fragments streamed from L2 ----
    int mi = lane & 15, quad = lane >> 4;
    floatx4 acc[10][4];
    #pragma unroll
    for (int a = 0; a < 10; a++)
        #pragma unroll
        for (int b2 = 0; b2 < 4; b2++) acc[a][b2] = (floatx4)0.f;

    const ushort_t* W0g = W0 + (size_t)g * 192 * 192;
    const ushort_t* W1g = W1 + (size_t)g * 256 * 256;
    const ushort_t* W2g = W2 + (size_t)g * 128 * 128;

    if (w == 0) {
        gemm_seg<192, 10>(acc, W0g, X0L, mi, quad);                       // Y0 cols 0..159
    } else if (w == 1) {
        gemm_seg<256, 8>(acc, W1g, X1L, mi, quad);                        // Y1 cols 0..127
    } else if (w == 2) {
        gemm_seg<256, 8>(acc, W1g + (size_t)128 * 256, X1L, mi, quad);    // Y1 cols 128..255
    } else {
        gemm_seg<192, 2>(acc, W0g + (size_t)160 * 192, X0L, mi, quad);    // Y0 cols 160..191
        gemm_seg<128, 8>(acc + 2, W2g, X2L, mi, quad);                    // Y2 cols 0..127
    }

    __syncthreads();   // everyone done reading X from LDS

    const float* B0g = B0 + g * 192;
    if (w == 0) {
        ywrite<192, 10, true>(acc, X0L, 0, B0g, mi, quad);
    } else if (w == 1) {
        ywrite<256, 8, false>(acc, X1L, 0, nullptr, mi, quad);
    } else if (w == 2) {
        ywrite<256, 8, false>(acc, X1L, 128, nullptr, mi, quad);
    } else {
        ywrite<192, 2, true>(acc, X0L, 160, B0g, mi, quad);
        ywrite<128, 8, false>(acc + 2, X2L, 0, nullptr, mi, quad);
    }
    __syncthreads();

    // ---- phase C: inverse rotate Y(LDS) -> out ----
    for (int i = 0; i < 16; i++) {
        int nl = w * 16 + i;
        float sa = -TR[nl * 6 + 0], ca = TR[nl * 6 + 1];
        float sb = -TR[nl * 6 + 2], cb = TR[nl * 6 + 3];
        float sg = -TR[nl * 6 + 4], cg = TR[nl * 6 + 5];
        float s2a = 2.f * sa * ca, c2a = ca * ca - sa * sa;
        float s2b = 2.f * sb * cb, c2b = cb * cb - sb * sb;
        float s2g = 2.f * sg * cg, c2g = cg * cg - sg * sg;

        float* orow = out + (size_t)(base + nl) * 576;

        orow[c] = yread(X0L, nl, c, 192);

        float v0 = yread(X1L, nl, c, 256);
        float v1 = yread(X0L, nl, 64 + c, 192);
        float v2 = yread(X1L, nl, 128 + c, 256);
        zrot1(v0, v2, ca, sa);
        j1mul(J1, v0, v1, v2);
        zrot1(v0, v2, cb, sb);
        j1mul(J1, v0, v1, v2);
        zrot1(v0, v2, cg, sg);
        orow[64 + 3 * c]     = v0;
        orow[64 + 3 * c + 1] = v1;
        orow[64 + 3 * c + 2] = v2;

        float u0 = yread(X2L, nl, c, 128);
        float u1 = yread(X1L, nl, 64 + c, 256);
        float u2 = yread(X0L, nl, 128 + c, 192);
        float u3 = yread(X1L, nl, 192 + c, 256);
        float u4 = yread(X2L, nl, 64 + c, 128);
        zrot2(u0, u1, u3, u4, ca, sa, c2a, s2a);
        j2mul(J2, u0, u1, u2, u3, u4);
        zrot2(u0, u1, u3, u4, cb, sb, c2b, s2b);
        j2mul(J2, u0, u1, u2, u3, u4);
        zrot2(u0, u1, u3, u4, cg, sg, c2g, s2g);
        orow[256 + 5 * c]     = u0;
        orow[256 + 5 * c + 1] = u1;
        orow[256 + 5 * c + 2] = u2;
        orow[256 + 5 * c + 3] = u3;
        orow[256 + 5 * c + 4] = u4;
    }
}

extern "C" void kernel_launch(void* const* d_in, const int* in_sizes, int n_in,
                              void* d_out, int out_size, void* d_ws, size_t ws_size,
                              hipStream_t stream)
{
    const float* x      = (const float*)d_in[0];
    const float* alpha  = (const float*)d_in[1];
    const float* beta   = (const float*)d_in[2];
    const float* gamma_ = (const float*)d_in[3];
    const float* coef   = (const float*)d_in[4];
    const float* Jd1    = (const float*)d_in[5];
    const float* Jd2    = (const float*)d_in[6];
    const float* w_m0   = (const float*)d_in[7];
    const float* b_m0   = (const float*)d_in[8];
    const float* ws_m0  = (const float*)d_in[9];
    const float* bs_m0  = (const float*)d_in[10];
    const float* w_m1   = (const float*)d_in[11];
    const float* ws_m1  = (const float*)d_in[12];
    const float* w_m2   = (const float*)d_in[13];
    const float* ws_m2  = (const float*)d_in[14];

    char* wsb = (char*)d_ws;
    ushort_t* W0 = (ushort_t*)(wsb + BY_W0);
    ushort_t* W1 = (ushort_t*)(wsb + BY_W1);
    ushort_t* W2 = (ushort_t*)(wsb + BY_W2);
    float*    B0 = (float*)(wsb + BY_B0);
    float*    out = (float*)d_out;

    hipLaunchKernelGGL(mix_kernel, dim3(3718), dim3(256), 0, stream,
                       coef, w_m0, b_m0, ws_m0, bs_m0, w_m1, ws_m1, w_m2, ws_m2,
                       W0, B0, W1, W2);
    hipLaunchKernelGGL(fused_kernel, dim3(1000), dim3(256), 0, stream,
                       x, alpha, beta, gamma_, Jd1, Jd2, W0, W1, W2, B0, out);
}